// Round 7
// baseline (364.297 us; speedup 1.0000x reference)
//
#include <hip/hip_runtime.h>

#define TT 16384
#define HH 1024
#define EE 8

typedef __attribute__((ext_vector_type(8))) short short8;
typedef __attribute__((ext_vector_type(4))) float f32x4;

__device__ inline unsigned short f2bf(float f) {
    union { float f; unsigned int u; } v; v.f = f;
    unsigned int u = v.u;
    unsigned int r = (u + 0x7FFFu + ((u >> 16) & 1u)) >> 16; // RNE
    return (unsigned short)r;
}

// ---------------------------------------------------------------------------
// Transpose + convert expert_w [E][H][H] fp32 (h-major) -> Wt [E][d][h] bf16
// ---------------------------------------------------------------------------
__global__ __launch_bounds__(256) void transpose_w_kernel(
    const float* __restrict__ w, unsigned short* __restrict__ wt)
{
    __shared__ unsigned short tile[64][66];
    int bid = blockIdx.x;
    int e   = bid >> 8;
    int rem = bid & 255;
    int hb  = ((rem >> 4) & 15) * 64;
    int db  = (rem & 15) * 64;
    int tid = threadIdx.x;
    int c4  = (tid & 15) * 4;
    int r0  = tid >> 4;

    const float* we = w + (size_t)e * HH * HH;
    #pragma unroll
    for (int i = 0; i < 4; ++i) {
        int r = i * 16 + r0;
        float4 v = *(const float4*)(we + (size_t)(hb + r) * HH + db + c4);
        tile[r][c4 + 0] = f2bf(v.x);
        tile[r][c4 + 1] = f2bf(v.y);
        tile[r][c4 + 2] = f2bf(v.z);
        tile[r][c4 + 3] = f2bf(v.w);
    }
    __syncthreads();
    unsigned short* wte = wt + (size_t)e * HH * HH;
    #pragma unroll
    for (int i = 0; i < 4; ++i) {
        int dr = i * 16 + r0;
        ushort4 o;
        o.x = tile[c4 + 0][dr];
        o.y = tile[c4 + 1][dr];
        o.z = tile[c4 + 2][dr];
        o.w = tile[c4 + 3][dr];
        *(ushort4*)(wte + (size_t)(db + dr) * HH + hb + c4) = o;
    }
}

// ---------------------------------------------------------------------------
// Router logits ONLY: wave-per-token, gw in LDS, fp32-exact, butterfly
// reduce, write logits + packed top-2. No stores in the load path ->
// loads stay in flight, latency hidden by occupancy.
// ---------------------------------------------------------------------------
__global__ __launch_bounds__(256) void router_logits_kernel(
    const float* __restrict__ x, const float* __restrict__ gw,
    const float* __restrict__ gb, float* __restrict__ logits,
    int* __restrict__ tops_i, float* __restrict__ tops_w)
{
    __shared__ float gwt[EE][HH];   // 32 KB: gwt[e][h] = gw[h][e]
    int tid = threadIdx.x;
    for (int i = tid; i < (HH * EE) / 4; i += 256) {
        float4 v = ((const float4*)gw)[i];
        int b4 = i * 4;
        gwt[(b4 + 0) & 7][(b4 + 0) >> 3] = v.x;
        gwt[(b4 + 1) & 7][(b4 + 1) >> 3] = v.y;
        gwt[(b4 + 2) & 7][(b4 + 2) >> 3] = v.z;
        gwt[(b4 + 3) & 7][(b4 + 3) >> 3] = v.w;
    }
    __syncthreads();

    const int lane = tid & 63;
    const int wv   = tid >> 6;
    const int t    = blockIdx.x * 4 + wv;
    const float* xrow = x + (size_t)t * HH;

    // 4 independent float4 loads, all issued before use
    float4 v0 = *(const float4*)(xrow + 0 * 256 + lane * 4);
    float4 v1 = *(const float4*)(xrow + 1 * 256 + lane * 4);
    float4 v2 = *(const float4*)(xrow + 2 * 256 + lane * 4);
    float4 v3 = *(const float4*)(xrow + 3 * 256 + lane * 4);

    float acc[8];
    #pragma unroll
    for (int e = 0; e < 8; ++e) {
        float4 g0 = *(const float4*)(&gwt[e][0 * 256 + lane * 4]);
        float4 g1 = *(const float4*)(&gwt[e][1 * 256 + lane * 4]);
        float4 g2 = *(const float4*)(&gwt[e][2 * 256 + lane * 4]);
        float4 g3 = *(const float4*)(&gwt[e][3 * 256 + lane * 4]);
        acc[e] = v0.x * g0.x + v0.y * g0.y + v0.z * g0.z + v0.w * g0.w
               + v1.x * g1.x + v1.y * g1.y + v1.z * g1.z + v1.w * g1.w
               + v2.x * g2.x + v2.y * g2.y + v2.z * g2.z + v2.w * g2.w
               + v3.x * g3.x + v3.y * g3.y + v3.z * g3.z + v3.w * g3.w;
    }
    #pragma unroll
    for (int e = 0; e < 8; ++e) {
        #pragma unroll
        for (int off = 32; off >= 1; off >>= 1)
            acc[e] += __shfl_xor(acc[e], off, 64);
    }
    float lg[8];
    #pragma unroll
    for (int e = 0; e < 8; ++e) lg[e] = acc[e] + gb[e];

    float myv = 0.0f;
    #pragma unroll
    for (int e = 0; e < 8; ++e) myv = (lane == e) ? lg[e] : myv;
    if (lane < 8) logits[(size_t)t * EE + lane] = myv;

    // top-2, lowest-index tie-break (matches lax.top_k; softmax monotone)
    int i0 = 0;
    #pragma unroll
    for (int e = 1; e < 8; ++e) if (lg[e] > lg[i0]) i0 = e;
    int i1 = (i0 == 0) ? 1 : 0;
    #pragma unroll
    for (int e = 0; e < 8; ++e) if (e != i0 && lg[e] > lg[i1]) i1 = e;

    float w0 = 1.0f / (1.0f + expf(lg[i1] - lg[i0])); // = p0/(p0+p1)

    if (lane == 0) {
        tops_i[t] = i0 | (i1 << 3);
        tops_w[t] = w0;
    }
}

// ---------------------------------------------------------------------------
// R2: build gather lists hierarchically (LDS histogram, 8 global atomics
// per block of 256 tokens).
// ---------------------------------------------------------------------------
__global__ __launch_bounds__(256) void build_lists_kernel(
    const int* __restrict__ tops_i, const float* __restrict__ tops_w,
    int* __restrict__ counts, int* __restrict__ tokl, float* __restrict__ wl)
{
    __shared__ int lcnt[EE];
    __shared__ int gbase[EE];
    int tid = threadIdx.x;
    if (tid < EE) lcnt[tid] = 0;
    __syncthreads();

    int t   = blockIdx.x * 256 + tid;
    int rec = tops_i[t];
    int i0  = rec & 7;
    int i1  = (rec >> 3) & 7;
    float w0 = tops_w[t];
    float w1 = 1.0f - w0;

    int r0 = atomicAdd(&lcnt[i0], 1);
    int r1 = atomicAdd(&lcnt[i1], 1);
    __syncthreads();

    if (tid < EE) gbase[tid] = atomicAdd(&counts[tid], lcnt[tid]);
    __syncthreads();

    int p0 = gbase[i0] + r0;
    tokl[i0 * TT + p0] = t; wl[i0 * TT + p0] = w0;
    int p1 = gbase[i1] + r1;
    tokl[i1 * TT + p1] = t; wl[i1 * TT + p1] = w1;
}

// ---------------------------------------------------------------------------
// Streaming init: grid-stride over float4s. x -> bf16 (xb) and
// out = w0*eb[i0] + w1*eb[i1]. Every iteration independent -> full MLP,
// near-HBM-BW. eb (32 KB) and tops (128 KB) are L2-resident broadcasts.
// ---------------------------------------------------------------------------
__global__ __launch_bounds__(256) void stream_init_kernel(
    const float* __restrict__ x, const float* __restrict__ eb,
    const int* __restrict__ tops_i, const float* __restrict__ tops_w,
    unsigned short* __restrict__ xb, float* __restrict__ out)
{
    const int N4 = TT * HH / 4;               // 4M float4s
    int stride = gridDim.x * 256;
    for (int f = blockIdx.x * 256 + threadIdx.x; f < N4; f += stride) {
        int t  = f >> 8;                      // 256 float4 per token row
        int c4 = f & 255;
        int rec = tops_i[t];
        int i0  = rec & 7;
        int i1  = (rec >> 3) & 7;
        float w0 = tops_w[t];
        float w1 = 1.0f - w0;

        float4 v = ((const float4*)x)[f];
        ushort4 bv;
        bv.x = f2bf(v.x); bv.y = f2bf(v.y); bv.z = f2bf(v.z); bv.w = f2bf(v.w);
        ((ushort4*)xb)[f] = bv;

        float4 a = *(const float4*)(eb + (size_t)i0 * HH + c4 * 4);
        float4 c = *(const float4*)(eb + (size_t)i1 * HH + c4 * 4);
        float4 r;
        r.x = w0 * a.x + w1 * c.x;
        r.y = w0 * a.y + w1 * c.y;
        r.z = w0 * a.z + w1 * c.z;
        r.w = w0 * a.w + w1 * c.w;
        ((float4*)out)[f] = r;
    }
}

// ---------------------------------------------------------------------------
// Grouped gathered GEMM (round-4 structure: single-buffered, 33.8 KB LDS,
// occupancy-friendly) + hoisted gather bases. 128x128 tile, BK=64, 4 waves,
// 16x16x32 bf16 MFMA, atomicAdd epilogue. XCD-pinned experts (T1).
// ---------------------------------------------------------------------------
#define BM 128
#define BN 128
#define BK 64

__global__ __launch_bounds__(256) void moe_gemm_kernel(
    const unsigned short* __restrict__ xb, const unsigned short* __restrict__ wt,
    const int* __restrict__ counts, const int* __restrict__ tokl,
    const float* __restrict__ wl, float* __restrict__ out)
{
    int bid = blockIdx.x;
    int e   = bid & 7;            // expert == XCD (grid % 8 == 0)
    int j   = bid >> 3;
    int mb  = j >> 3;
    int nb  = j & 7;
    int cnt = counts[e];
    int row0 = mb * BM;
    if (row0 >= cnt) return;

    __shared__ __align__(16) unsigned short Alds[BM * BK];
    __shared__ __align__(16) unsigned short Blds[BN * BK];
    __shared__ int   toks[BM];
    __shared__ float wgts[BM];

    int tid = threadIdx.x;
    if (tid < BM) {
        int g = row0 + tid;
        bool ok = g < cnt;
        toks[tid] = ok ? tokl[e * TT + g] : 0;
        wgts[tid] = ok ? wl[e * TT + g] : 0.0f;
    }
    __syncthreads();

    const int lane = tid & 63;
    const int wv   = tid >> 6;
    const int wr   = wv >> 1, wc = wv & 1;
    const int mrow = wr * 64, ncol = wc * 64;

    f32x4 acc[4][4];
    #pragma unroll
    for (int m = 0; m < 4; ++m)
        #pragma unroll
        for (int n = 0; n < 4; ++n) acc[m][n] = (f32x4)0.0f;

    const unsigned short* wte = wt + (size_t)e * HH * HH + (size_t)(nb * BN) * HH;
    const int off = wv * 1024 + lane * 16;

    // hoist per-round gather bases (k0-invariant)
    const unsigned short* abase[4];
    const unsigned short* bbase[4];
    #pragma unroll
    for (int rnd = 0; rnd < 4; ++rnd) {
        int o  = rnd * 4096 + off;
        int r  = o >> 7;          // tile row (128 B per row)
        int cb = (o & 127) >> 1;  // element offset within row
        abase[rnd] = xb + (size_t)toks[r] * HH + cb;
        bbase[rnd] = wte + (size_t)r * HH + cb;
    }

    for (int kt = 0; kt < HH / BK; ++kt) {
        int k0 = kt * BK;
        #pragma unroll
        for (int rnd = 0; rnd < 4; ++rnd) {
            __builtin_amdgcn_global_load_lds(
                (const __attribute__((address_space(1))) void*)(abase[rnd] + k0),
                (__attribute__((address_space(3))) void*)((char*)Alds + rnd * 4096 + wv * 1024),
                16, 0, 0);
            __builtin_amdgcn_global_load_lds(
                (const __attribute__((address_space(1))) void*)(bbase[rnd] + k0),
                (__attribute__((address_space(3))) void*)((char*)Blds + rnd * 4096 + wv * 1024),
                16, 0, 0);
        }
        __syncthreads();
        #pragma unroll
        for (int kk = 0; kk < 2; ++kk) {
            int kb = kk * 64 + (lane >> 4) * 16;
            short8 av[4], bv[4];
            #pragma unroll
            for (int m = 0; m < 4; ++m)
                av[m] = *(const short8*)((const char*)Alds + (mrow + m * 16 + (lane & 15)) * 128 + kb);
            #pragma unroll
            for (int n = 0; n < 4; ++n)
                bv[n] = *(const short8*)((const char*)Blds + (ncol + n * 16 + (lane & 15)) * 128 + kb);
            #pragma unroll
            for (int m = 0; m < 4; ++m)
                #pragma unroll
                for (int n = 0; n < 4; ++n)
                    acc[m][n] = __builtin_amdgcn_mfma_f32_16x16x32_bf16(av[m], bv[n], acc[m][n], 0, 0, 0);
        }
        __syncthreads();
    }

    // epilogue: C/D mapping col=lane&15, row=(lane>>4)*4+reg
    #pragma unroll
    for (int m = 0; m < 4; ++m) {
        int lr0 = mrow + m * 16 + ((lane >> 4) << 2);
        #pragma unroll
        for (int rg = 0; rg < 4; ++rg) {
            int lr = lr0 + rg;
            int tkn = toks[lr];
            float wg = wgts[lr];
            if (wg != 0.0f) {
                float* orow = out + (size_t)tkn * HH + nb * BN + ncol + (lane & 15);
                #pragma unroll
                for (int n = 0; n < 4; ++n)
                    atomicAdd(orow + n * 16, wg * acc[m][n][rg]);
            }
        }
    }
}

// ---------------------------------------------------------------------------
extern "C" void kernel_launch(void* const* d_in, const int* in_sizes, int n_in,
                              void* d_out, int out_size, void* d_ws, size_t ws_size,
                              hipStream_t stream) {
    const float* x  = (const float*)d_in[0];
    const float* gw = (const float*)d_in[1];
    const float* gb = (const float*)d_in[2];
    const float* ew = (const float*)d_in[3];
    const float* eb = (const float*)d_in[4];
    float* out    = (float*)d_out;
    float* logits = out + (size_t)TT * HH;

    char* w = (char*)d_ws;
    unsigned short* xb = (unsigned short*)w;                                   // 32 MB
    unsigned short* wt = (unsigned short*)(w + (size_t)TT * HH * 2);           // 16 MB
    char* p  = w + (size_t)TT * HH * 2 + (size_t)EE * HH * HH * 2;
    int*   counts = (int*)p;                                                   // 32 B (+pad)
    int*   tokl   = (int*)(p + 256);                                           // 512 KB
    float* wl     = (float*)(p + 256 + (size_t)EE * TT * 4);                   // 512 KB
    int*   tops_i = (int*)(p + 256 + 2 * (size_t)EE * TT * 4);                 // 64 KB
    float* tops_w = (float*)(p + 256 + 2 * (size_t)EE * TT * 4 + TT * 4);      // 64 KB

    hipMemsetAsync(counts, 0, 256, stream);
    hipLaunchKernelGGL(transpose_w_kernel, dim3(EE * 256), dim3(256), 0, stream, ew, wt);
    hipLaunchKernelGGL(router_logits_kernel, dim3(TT / 4), dim3(256), 0, stream,
                       x, gw, gb, logits, tops_i, tops_w);
    hipLaunchKernelGGL(build_lists_kernel, dim3(TT / 256), dim3(256), 0, stream,
                       tops_i, tops_w, counts, tokl, wl);
    hipLaunchKernelGGL(stream_init_kernel, dim3(2048), dim3(256), 0, stream,
                       x, eb, tops_i, tops_w, xb, out);
    hipLaunchKernelGGL(moe_gemm_kernel, dim3(EE * (TT / BM) * (HH / BN)), dim3(256), 0, stream,
                       xb, wt, counts, tokl, wl, out);
}

// Round 9
// 333.448 us; speedup vs baseline: 1.0925x; 1.0925x over previous
//
#include <hip/hip_runtime.h>

#define TT 16384
#define HH 1024
#define EE 8

typedef __attribute__((ext_vector_type(8))) short short8;
typedef __attribute__((ext_vector_type(4))) float f32x4;

__device__ inline unsigned short f2bf(float f) {
    union { float f; unsigned int u; } v; v.f = f;
    unsigned int u = v.u;
    unsigned int r = (u + 0x7FFFu + ((u >> 16) & 1u)) >> 16; // RNE
    return (unsigned short)r;
}

// ---------------------------------------------------------------------------
// Transpose + convert expert_w [E][H][H] fp32 (h-major) -> Wt [E][d][h] bf16
// ---------------------------------------------------------------------------
__global__ __launch_bounds__(256) void transpose_w_kernel(
    const float* __restrict__ w, unsigned short* __restrict__ wt)
{
    __shared__ unsigned short tile[64][66];
    int bid = blockIdx.x;
    int e   = bid >> 8;
    int rem = bid & 255;
    int hb  = ((rem >> 4) & 15) * 64;
    int db  = (rem & 15) * 64;
    int tid = threadIdx.x;
    int c4  = (tid & 15) * 4;
    int r0  = tid >> 4;

    const float* we = w + (size_t)e * HH * HH;
    #pragma unroll
    for (int i = 0; i < 4; ++i) {
        int r = i * 16 + r0;
        float4 v = *(const float4*)(we + (size_t)(hb + r) * HH + db + c4);
        tile[r][c4 + 0] = f2bf(v.x);
        tile[r][c4 + 1] = f2bf(v.y);
        tile[r][c4 + 2] = f2bf(v.z);
        tile[r][c4 + 3] = f2bf(v.w);
    }
    __syncthreads();
    unsigned short* wte = wt + (size_t)e * HH * HH;
    #pragma unroll
    for (int i = 0; i < 4; ++i) {
        int dr = i * 16 + r0;
        ushort4 o;
        o.x = tile[c4 + 0][dr];
        o.y = tile[c4 + 1][dr];
        o.z = tile[c4 + 2][dr];
        o.w = tile[c4 + 3][dr];
        *(ushort4*)(wte + (size_t)(db + dr) * HH + hb + c4) = o;
    }
}

// ---------------------------------------------------------------------------
// Router logits: wave-per-token, gw in LDS, fp32-exact, butterfly reduce,
// write logits + packed top-2.
// ---------------------------------------------------------------------------
__global__ __launch_bounds__(256) void router_logits_kernel(
    const float* __restrict__ x, const float* __restrict__ gw,
    const float* __restrict__ gb, float* __restrict__ logits,
    int* __restrict__ tops_i, float* __restrict__ tops_w)
{
    __shared__ float gwt[EE][HH];   // 32 KB: gwt[e][h] = gw[h][e]
    int tid = threadIdx.x;
    for (int i = tid; i < (HH * EE) / 4; i += 256) {
        float4 v = ((const float4*)gw)[i];
        int b4 = i * 4;
        gwt[(b4 + 0) & 7][(b4 + 0) >> 3] = v.x;
        gwt[(b4 + 1) & 7][(b4 + 1) >> 3] = v.y;
        gwt[(b4 + 2) & 7][(b4 + 2) >> 3] = v.z;
        gwt[(b4 + 3) & 7][(b4 + 3) >> 3] = v.w;
    }
    __syncthreads();

    const int lane = tid & 63;
    const int wv   = tid >> 6;
    const int t    = blockIdx.x * 4 + wv;
    const float* xrow = x + (size_t)t * HH;

    float4 v0 = *(const float4*)(xrow + 0 * 256 + lane * 4);
    float4 v1 = *(const float4*)(xrow + 1 * 256 + lane * 4);
    float4 v2 = *(const float4*)(xrow + 2 * 256 + lane * 4);
    float4 v3 = *(const float4*)(xrow + 3 * 256 + lane * 4);

    float acc[8];
    #pragma unroll
    for (int e = 0; e < 8; ++e) {
        float4 g0 = *(const float4*)(&gwt[e][0 * 256 + lane * 4]);
        float4 g1 = *(const float4*)(&gwt[e][1 * 256 + lane * 4]);
        float4 g2 = *(const float4*)(&gwt[e][2 * 256 + lane * 4]);
        float4 g3 = *(const float4*)(&gwt[e][3 * 256 + lane * 4]);
        acc[e] = v0.x * g0.x + v0.y * g0.y + v0.z * g0.z + v0.w * g0.w
               + v1.x * g1.x + v1.y * g1.y + v1.z * g1.z + v1.w * g1.w
               + v2.x * g2.x + v2.y * g2.y + v2.z * g2.z + v2.w * g2.w
               + v3.x * g3.x + v3.y * g3.y + v3.z * g3.z + v3.w * g3.w;
    }
    #pragma unroll
    for (int e = 0; e < 8; ++e) {
        #pragma unroll
        for (int off = 32; off >= 1; off >>= 1)
            acc[e] += __shfl_xor(acc[e], off, 64);
    }
    float lg[8];
    #pragma unroll
    for (int e = 0; e < 8; ++e) lg[e] = acc[e] + gb[e];

    float myv = 0.0f;
    #pragma unroll
    for (int e = 0; e < 8; ++e) myv = (lane == e) ? lg[e] : myv;
    if (lane < 8) logits[(size_t)t * EE + lane] = myv;

    // top-2, lowest-index tie-break (matches lax.top_k; softmax monotone)
    int i0 = 0;
    #pragma unroll
    for (int e = 1; e < 8; ++e) if (lg[e] > lg[i0]) i0 = e;
    int i1 = (i0 == 0) ? 1 : 0;
    #pragma unroll
    for (int e = 0; e < 8; ++e) if (e != i0 && lg[e] > lg[i1]) i1 = e;

    float w0 = 1.0f / (1.0f + expf(lg[i1] - lg[i0])); // = p0/(p0+p1)

    if (lane == 0) {
        tops_i[t] = i0 | (i1 << 3);
        tops_w[t] = w0;
    }
}

// ---------------------------------------------------------------------------
// Build gather lists hierarchically (LDS histogram, 8 global atomics/block).
// ---------------------------------------------------------------------------
__global__ __launch_bounds__(256) void build_lists_kernel(
    const int* __restrict__ tops_i, const float* __restrict__ tops_w,
    int* __restrict__ counts, int* __restrict__ tokl, float* __restrict__ wl)
{
    __shared__ int lcnt[EE];
    __shared__ int gbase[EE];
    int tid = threadIdx.x;
    if (tid < EE) lcnt[tid] = 0;
    __syncthreads();

    int t   = blockIdx.x * 256 + tid;
    int rec = tops_i[t];
    int i0  = rec & 7;
    int i1  = (rec >> 3) & 7;
    float w0 = tops_w[t];
    float w1 = 1.0f - w0;

    int r0 = atomicAdd(&lcnt[i0], 1);
    int r1 = atomicAdd(&lcnt[i1], 1);
    __syncthreads();

    if (tid < EE) gbase[tid] = atomicAdd(&counts[tid], lcnt[tid]);
    __syncthreads();

    int p0 = gbase[i0] + r0;
    tokl[i0 * TT + p0] = t; wl[i0 * TT + p0] = w0;
    int p1 = gbase[i1] + r1;
    tokl[i1 * TT + p1] = t; wl[i1 * TT + p1] = w1;
}

// ---------------------------------------------------------------------------
// Streaming init: x -> bf16 (xb) and out = w0*eb[i0] + w1*eb[i1].
// ---------------------------------------------------------------------------
__global__ __launch_bounds__(256) void stream_init_kernel(
    const float* __restrict__ x, const float* __restrict__ eb,
    const int* __restrict__ tops_i, const float* __restrict__ tops_w,
    unsigned short* __restrict__ xb, float* __restrict__ out)
{
    const int N4 = TT * HH / 4;               // 4M float4s
    int stride = gridDim.x * 256;
    for (int f = blockIdx.x * 256 + threadIdx.x; f < N4; f += stride) {
        int t  = f >> 8;
        int c4 = f & 255;
        int rec = tops_i[t];
        int i0  = rec & 7;
        int i1  = (rec >> 3) & 7;
        float w0 = tops_w[t];
        float w1 = 1.0f - w0;

        float4 v = ((const float4*)x)[f];
        ushort4 bv;
        bv.x = f2bf(v.x); bv.y = f2bf(v.y); bv.z = f2bf(v.z); bv.w = f2bf(v.w);
        ((ushort4*)xb)[f] = bv;

        float4 a = *(const float4*)(eb + (size_t)i0 * HH + c4 * 4);
        float4 c = *(const float4*)(eb + (size_t)i1 * HH + c4 * 4);
        float4 r;
        r.x = w0 * a.x + w1 * c.x;
        r.y = w0 * a.y + w1 * c.y;
        r.z = w0 * a.z + w1 * c.z;
        r.w = w0 * a.w + w1 * c.w;
        ((float4*)out)[f] = r;
    }
}

// ---------------------------------------------------------------------------
// Grouped gathered GEMM with COUNTED-vmcnt double-buffer (T3+T4 minimum):
// BK=32 so 2x(A+B) LDS = 32 KB (same footprint as single-buffered BK=64 ->
// occupancy preserved, unlike round-5's 66 KB). Raw s_barrier + vmcnt(4):
// next tile's 4 global_load_lds stay in flight across the barrier.
// 128x128 tile, 4 waves, 16x16x32 bf16 MFMA, atomicAdd epilogue, XCD-pinned.
// ---------------------------------------------------------------------------
#define BM 128
#define BN 128
#define BK 32
#define NT (HH / BK)   // 32 K-steps

__global__ __launch_bounds__(256) void moe_gemm_kernel(
    const unsigned short* __restrict__ xb, const unsigned short* __restrict__ wt,
    const int* __restrict__ counts, const int* __restrict__ tokl,
    const float* __restrict__ wl, float* __restrict__ out)
{
    int bid = blockIdx.x;
    int e   = bid & 7;            // expert == XCD (grid % 8 == 0)
    int j   = bid >> 3;
    int mb  = j >> 3;
    int nb  = j & 7;
    int cnt = counts[e];
    int row0 = mb * BM;
    if (row0 >= cnt) return;

    __shared__ __align__(16) unsigned short Alds[2][BM * BK]; // 2 x 8 KB
    __shared__ __align__(16) unsigned short Blds[2][BN * BK]; // 2 x 8 KB
    __shared__ int   toks[BM];
    __shared__ float wgts[BM];

    int tid = threadIdx.x;
    if (tid < BM) {
        int g = row0 + tid;
        bool ok = g < cnt;
        toks[tid] = ok ? tokl[e * TT + g] : 0;
        wgts[tid] = ok ? wl[e * TT + g] : 0.0f;
    }
    __syncthreads();

    const int lane = tid & 63;
    const int wv   = tid >> 6;
    const int wr   = wv >> 1, wc = wv & 1;
    const int mrow = wr * 64, ncol = wc * 64;

    f32x4 acc[4][4];
    #pragma unroll
    for (int m = 0; m < 4; ++m)
        #pragma unroll
        for (int n = 0; n < 4; ++n) acc[m][n] = (f32x4)0.0f;

    const unsigned short* wte = wt + (size_t)e * HH * HH + (size_t)(nb * BN) * HH;

    // Staging geometry (BK=32, 64 B per tile row): thread covers bytes
    // tid*16 + i*4096 (i=0,1) of each 8 KB matrix buffer.
    //   row  = (tid>>2) + i*64   (4 lanes x 16 B per 64 B row)
    //   colE = (tid&3)*8         (element offset within row)
    const int srow = tid >> 2;
    const int scol = (tid & 3) * 8;
    const unsigned short* abase0 = xb + (size_t)toks[srow] * HH + scol;
    const unsigned short* abase1 = xb + (size_t)toks[srow + 64] * HH + scol;
    const unsigned short* bbase0 = wte + (size_t)srow * HH + scol;
    const unsigned short* bbase1 = wte + (size_t)(srow + 64) * HH + scol;
    const int ldst = tid * 16;    // linear LDS byte offset for instr i=0

#define STAGE(buf, k0)                                                         \
    {                                                                          \
        __builtin_amdgcn_global_load_lds(                                      \
            (const __attribute__((address_space(1))) void*)(abase0 + (k0)),    \
            (__attribute__((address_space(3))) void*)((char*)&Alds[buf][0] + ldst), \
            16, 0, 0);                                                         \
        __builtin_amdgcn_global_load_lds(                                      \
            (const __attribute__((address_space(1))) void*)(abase1 + (k0)),    \
            (__attribute__((address_space(3))) void*)((char*)&Alds[buf][0] + ldst + 4096), \
            16, 0, 0);                                                         \
        __builtin_amdgcn_global_load_lds(                                      \
            (const __attribute__((address_space(1))) void*)(bbase0 + (k0)),    \
            (__attribute__((address_space(3))) void*)((char*)&Blds[buf][0] + ldst), \
            16, 0, 0);                                                         \
        __builtin_amdgcn_global_load_lds(                                      \
            (const __attribute__((address_space(1))) void*)(bbase1 + (k0)),    \
            (__attribute__((address_space(3))) void*)((char*)&Blds[buf][0] + ldst + 4096), \
            16, 0, 0);                                                         \
    }

    // COMPUTE(buf): one 16x16x32 MFMA per (m,n); rows are 64 B in LDS.
#define COMPUTE(buf)                                                           \
    {                                                                          \
        int kb = (lane >> 4) * 16;                                             \
        short8 av[4], bv[4];                                                   \
        _Pragma("unroll")                                                      \
        for (int m = 0; m < 4; ++m)                                            \
            av[m] = *(const short8*)((const char*)&Alds[buf][0] + (mrow + m * 16 + (lane & 15)) * 64 + kb); \
        _Pragma("unroll")                                                      \
        for (int n = 0; n < 4; ++n)                                            \
            bv[n] = *(const short8*)((const char*)&Blds[buf][0] + (ncol + n * 16 + (lane & 15)) * 64 + kb); \
        _Pragma("unroll")                                                      \
        for (int m = 0; m < 4; ++m)                                            \
            _Pragma("unroll")                                                  \
            for (int n = 0; n < 4; ++n)                                        \
                acc[m][n] = __builtin_amdgcn_mfma_f32_16x16x32_bf16(av[m], bv[n], acc[m][n], 0, 0, 0); \
    }

    // prologue: stage tile 0 into buf 0 (4 loads in flight)
    STAGE(0, 0);

    // main loop: iterations kt = 0..NT-2; stage kt+1 into the other buffer,
    // then wait ONLY for cur's 4 loads (vmcnt(4): next's 4 stay in flight).
    for (int kt = 0; kt < NT - 1; kt += 2) {
        // --- even step: cur = buf0, stage into buf1 ---
        STAGE(1, (kt + 1) * BK);
        asm volatile("s_waitcnt vmcnt(4)" ::: "memory");
        __builtin_amdgcn_sched_barrier(0);
        __builtin_amdgcn_s_barrier();
        __builtin_amdgcn_sched_barrier(0);
        COMPUTE(0);
        __builtin_amdgcn_sched_barrier(0);
        __builtin_amdgcn_s_barrier();   // all waves done reading buf0
        __builtin_amdgcn_sched_barrier(0);
        // --- odd step: cur = buf1, stage into buf0 (unless last) ---
        if (kt + 2 < NT) {
            STAGE(0, (kt + 2) * BK);
            asm volatile("s_waitcnt vmcnt(4)" ::: "memory");
        } else {
            asm volatile("s_waitcnt vmcnt(0)" ::: "memory");
        }
        __builtin_amdgcn_sched_barrier(0);
        __builtin_amdgcn_s_barrier();
        __builtin_amdgcn_sched_barrier(0);
        COMPUTE(1);
        __builtin_amdgcn_sched_barrier(0);
        __builtin_amdgcn_s_barrier();
        __builtin_amdgcn_sched_barrier(0);
    }
    // tail: NT=32 even -> kt=30 stages tile 31 into buf1, computes tiles 30
    // (buf0) and 31 (buf1); the kt+2<NT branch is false -> vmcnt(0) drain.
    {
        asm volatile("s_waitcnt vmcnt(0)" ::: "memory");
        __builtin_amdgcn_sched_barrier(0);
    }

#undef STAGE
#undef COMPUTE

    // epilogue: C/D mapping col=lane&15, row=(lane>>4)*4+reg
    #pragma unroll
    for (int m = 0; m < 4; ++m) {
        int lr0 = mrow + m * 16 + ((lane >> 4) << 2);
        #pragma unroll
        for (int rg = 0; rg < 4; ++rg) {
            int lr = lr0 + rg;
            int tkn = toks[lr];
            float wg = wgts[lr];
            if (wg != 0.0f) {
                float* orow = out + (size_t)tkn * HH + nb * BN + ncol + (lane & 15);
                #pragma unroll
                for (int n = 0; n < 4; ++n)
                    atomicAdd(orow + n * 16, wg * acc[m][n][rg]);
            }
        }
    }
}

// ---------------------------------------------------------------------------
extern "C" void kernel_launch(void* const* d_in, const int* in_sizes, int n_in,
                              void* d_out, int out_size, void* d_ws, size_t ws_size,
                              hipStream_t stream) {
    const float* x  = (const float*)d_in[0];
    const float* gw = (const float*)d_in[1];
    const float* gb = (const float*)d_in[2];
    const float* ew = (const float*)d_in[3];
    const float* eb = (const float*)d_in[4];
    float* out    = (float*)d_out;
    float* logits = out + (size_t)TT * HH;

    char* w = (char*)d_ws;
    unsigned short* xb = (unsigned short*)w;                                   // 32 MB
    unsigned short* wt = (unsigned short*)(w + (size_t)TT * HH * 2);           // 16 MB
    char* p  = w + (size_t)TT * HH * 2 + (size_t)EE * HH * HH * 2;
    int*   counts = (int*)p;                                                   // 32 B (+pad)
    int*   tokl   = (int*)(p + 256);                                           // 512 KB
    float* wl     = (float*)(p + 256 + (size_t)EE * TT * 4);                   // 512 KB
    int*   tops_i = (int*)(p + 256 + 2 * (size_t)EE * TT * 4);                 // 64 KB
    float* tops_w = (float*)(p + 256 + 2 * (size_t)EE * TT * 4 + TT * 4);      // 64 KB

    hipMemsetAsync(counts, 0, 256, stream);
    hipLaunchKernelGGL(transpose_w_kernel, dim3(EE * 256), dim3(256), 0, stream, ew, wt);
    hipLaunchKernelGGL(router_logits_kernel, dim3(TT / 4), dim3(256), 0, stream,
                       x, gw, gb, logits, tops_i, tops_w);
    hipLaunchKernelGGL(build_lists_kernel, dim3(TT / 256), dim3(256), 0, stream,
                       tops_i, tops_w, counts, tokl, wl);
    hipLaunchKernelGGL(stream_init_kernel, dim3(2048), dim3(256), 0, stream,
                       x, eb, tops_i, tops_w, xb, out);
    hipLaunchKernelGGL(moe_gemm_kernel, dim3(EE * (TT / BM) * (HH / BN)), dim3(256), 0, stream,
                       xb, wt, counts, tokl, wl, out);
}

// Round 11
// 327.163 us; speedup vs baseline: 1.1135x; 1.0192x over previous
//
#include <hip/hip_runtime.h>

#define TT 16384
#define HH 1024
#define EE 8

typedef __attribute__((ext_vector_type(8))) short short8;
typedef __attribute__((ext_vector_type(4))) float f32x4;

__device__ inline unsigned short f2bf(float f) {
    union { float f; unsigned int u; } v; v.f = f;
    unsigned int u = v.u;
    unsigned int r = (u + 0x7FFFu + ((u >> 16) & 1u)) >> 16; // RNE
    return (unsigned short)r;
}

// ---------------------------------------------------------------------------
// Fused prep: blocks [0,2048) transpose expert_w -> Wt bf16 [E][d][h];
// blocks [2048,6144) compute router logits + packed top-2 (fp32 exact).
// Shared 32 KB smem region reused by both paths.
// ---------------------------------------------------------------------------
__global__ __launch_bounds__(256) void prep_kernel(
    const float* __restrict__ ew, unsigned short* __restrict__ wt,
    const float* __restrict__ x, const float* __restrict__ gw,
    const float* __restrict__ gb, float* __restrict__ logits,
    int* __restrict__ tops_i, float* __restrict__ tops_w)
{
    __shared__ __align__(16) char smem[EE * HH * 4];   // 32 KB
    int tid = threadIdx.x;

    if (blockIdx.x < 2048) {
        // ---- transpose path ----
        unsigned short (*tile)[66] = (unsigned short(*)[66])smem;
        int bid = blockIdx.x;
        int e   = bid >> 8;
        int rem = bid & 255;
        int hb  = ((rem >> 4) & 15) * 64;
        int db  = (rem & 15) * 64;
        int c4  = (tid & 15) * 4;
        int r0  = tid >> 4;

        const float* we = ew + (size_t)e * HH * HH;
        #pragma unroll
        for (int i = 0; i < 4; ++i) {
            int r = i * 16 + r0;
            float4 v = *(const float4*)(we + (size_t)(hb + r) * HH + db + c4);
            tile[r][c4 + 0] = f2bf(v.x);
            tile[r][c4 + 1] = f2bf(v.y);
            tile[r][c4 + 2] = f2bf(v.z);
            tile[r][c4 + 3] = f2bf(v.w);
        }
        __syncthreads();
        unsigned short* wte = wt + (size_t)e * HH * HH;
        #pragma unroll
        for (int i = 0; i < 4; ++i) {
            int dr = i * 16 + r0;
            ushort4 o;
            o.x = tile[c4 + 0][dr];
            o.y = tile[c4 + 1][dr];
            o.z = tile[c4 + 2][dr];
            o.w = tile[c4 + 3][dr];
            *(ushort4*)(wte + (size_t)(db + dr) * HH + hb + c4) = o;
        }
    } else {
        // ---- router path ----
        float (*gwt)[HH] = (float(*)[HH])smem;          // gwt[e][h] = gw[h][e]
        for (int i = tid; i < (HH * EE) / 4; i += 256) {
            float4 v = ((const float4*)gw)[i];
            int b4 = i * 4;
            gwt[(b4 + 0) & 7][(b4 + 0) >> 3] = v.x;
            gwt[(b4 + 1) & 7][(b4 + 1) >> 3] = v.y;
            gwt[(b4 + 2) & 7][(b4 + 2) >> 3] = v.z;
            gwt[(b4 + 3) & 7][(b4 + 3) >> 3] = v.w;
        }
        __syncthreads();

        const int lane = tid & 63;
        const int wv   = tid >> 6;
        const int t    = (blockIdx.x - 2048) * 4 + wv;
        const float* xrow = x + (size_t)t * HH;

        float4 v0 = *(const float4*)(xrow + 0 * 256 + lane * 4);
        float4 v1 = *(const float4*)(xrow + 1 * 256 + lane * 4);
        float4 v2 = *(const float4*)(xrow + 2 * 256 + lane * 4);
        float4 v3 = *(const float4*)(xrow + 3 * 256 + lane * 4);

        float acc[8];
        #pragma unroll
        for (int e = 0; e < 8; ++e) {
            float4 g0 = *(const float4*)(&gwt[e][0 * 256 + lane * 4]);
            float4 g1 = *(const float4*)(&gwt[e][1 * 256 + lane * 4]);
            float4 g2 = *(const float4*)(&gwt[e][2 * 256 + lane * 4]);
            float4 g3 = *(const float4*)(&gwt[e][3 * 256 + lane * 4]);
            acc[e] = v0.x * g0.x + v0.y * g0.y + v0.z * g0.z + v0.w * g0.w
                   + v1.x * g1.x + v1.y * g1.y + v1.z * g1.z + v1.w * g1.w
                   + v2.x * g2.x + v2.y * g2.y + v2.z * g2.z + v2.w * g2.w
                   + v3.x * g3.x + v3.y * g3.y + v3.z * g3.z + v3.w * g3.w;
        }
        #pragma unroll
        for (int e = 0; e < 8; ++e) {
            #pragma unroll
            for (int off = 32; off >= 1; off >>= 1)
                acc[e] += __shfl_xor(acc[e], off, 64);
        }
        float lg[8];
        #pragma unroll
        for (int e = 0; e < 8; ++e) lg[e] = acc[e] + gb[e];

        float myv = 0.0f;
        #pragma unroll
        for (int e = 0; e < 8; ++e) myv = (lane == e) ? lg[e] : myv;
        if (lane < 8) logits[(size_t)t * EE + lane] = myv;

        // top-2, lowest-index tie-break (matches lax.top_k; softmax monotone)
        int i0 = 0;
        #pragma unroll
        for (int e = 1; e < 8; ++e) if (lg[e] > lg[i0]) i0 = e;
        int i1 = (i0 == 0) ? 1 : 0;
        #pragma unroll
        for (int e = 0; e < 8; ++e) if (e != i0 && lg[e] > lg[i1]) i1 = e;

        float w0 = 1.0f / (1.0f + expf(lg[i1] - lg[i0])); // = p0/(p0+p1)

        if (lane == 0) {
            tops_i[t] = i0 | (i1 << 3);
            tops_w[t] = w0;
        }
    }
}

// ---------------------------------------------------------------------------
// Fused stream-init + list-build. All 2048 blocks stream (x -> bf16 xb,
// out = w0*eb[i0] + w1*eb[i1]); blocks [0,64) additionally build the gather
// lists for their 256 tokens (LDS histogram, 8 global atomics per block).
// Both parts only read tops_* written by the previous kernel.
// ---------------------------------------------------------------------------
__global__ __launch_bounds__(256) void stream_lists_kernel(
    const float* __restrict__ x, const float* __restrict__ eb,
    const int* __restrict__ tops_i, const float* __restrict__ tops_w,
    int* __restrict__ counts, int* __restrict__ tokl, float* __restrict__ wl,
    unsigned short* __restrict__ xb, float* __restrict__ out)
{
    int tid = threadIdx.x;

    if (blockIdx.x < TT / 256) {           // 64 list-builder blocks
        __shared__ int lcnt[EE];
        __shared__ int gbase[EE];
        if (tid < EE) lcnt[tid] = 0;
        __syncthreads();

        int t   = blockIdx.x * 256 + tid;
        int rec = tops_i[t];
        int i0  = rec & 7;
        int i1  = (rec >> 3) & 7;
        float w0 = tops_w[t];
        float w1 = 1.0f - w0;

        int r0 = atomicAdd(&lcnt[i0], 1);
        int r1 = atomicAdd(&lcnt[i1], 1);
        __syncthreads();

        if (tid < EE) gbase[tid] = atomicAdd(&counts[tid], lcnt[tid]);
        __syncthreads();

        int p0 = gbase[i0] + r0;
        tokl[i0 * TT + p0] = t; wl[i0 * TT + p0] = w0;
        int p1 = gbase[i1] + r1;
        tokl[i1 * TT + p1] = t; wl[i1 * TT + p1] = w1;
    }

    const int N4 = TT * HH / 4;            // 4M float4s
    int stride = gridDim.x * 256;
    for (int f = blockIdx.x * 256 + tid; f < N4; f += stride) {
        int t  = f >> 8;
        int c4 = f & 255;
        int rec = tops_i[t];
        int i0  = rec & 7;
        int i1  = (rec >> 3) & 7;
        float w0 = tops_w[t];
        float w1 = 1.0f - w0;

        float4 v = ((const float4*)x)[f];
        ushort4 bv;
        bv.x = f2bf(v.x); bv.y = f2bf(v.y); bv.z = f2bf(v.z); bv.w = f2bf(v.w);
        ((ushort4*)xb)[f] = bv;

        float4 a = *(const float4*)(eb + (size_t)i0 * HH + c4 * 4);
        float4 c = *(const float4*)(eb + (size_t)i1 * HH + c4 * 4);
        float4 r;
        r.x = w0 * a.x + w1 * c.x;
        r.y = w0 * a.y + w1 * c.y;
        r.z = w0 * a.z + w1 * c.z;
        r.w = w0 * a.w + w1 * c.w;
        ((float4*)out)[f] = r;
    }
}

// ---------------------------------------------------------------------------
// Grouped gathered GEMM, counted-vmcnt dbuf (BK=32, 32 KB LDS) + T2 chunk
// swizzle: LDS rows are 64 B (4 chunks of 16 B). Linear rows put 16 lanes on
// 2 banks (8-way conflict); XOR the chunk with row&3 on BOTH sides:
//   stage: source chunk = (tid&3) ^ ((tid>>2)&3), linear LDS dest (rule 21)
//   read:  chunk = (lane>>4) ^ (lane&3)    [row&3 == lane&3 for all frags]
// -> 4-way residual (max spread with 16B reads in 64B rows).
// ---------------------------------------------------------------------------
#define BM 128
#define BN 128
#define BK 32
#define NT (HH / BK)   // 32 K-steps

__global__ __launch_bounds__(256) void moe_gemm_kernel(
    const unsigned short* __restrict__ xb, const unsigned short* __restrict__ wt,
    const int* __restrict__ counts, const int* __restrict__ tokl,
    const float* __restrict__ wl, float* __restrict__ out)
{
    int bid = blockIdx.x;
    int e   = bid & 7;            // expert == XCD (grid % 8 == 0)
    int j   = bid >> 3;
    int mb  = j >> 3;
    int nb  = j & 7;
    int cnt = counts[e];
    int row0 = mb * BM;
    if (row0 >= cnt) return;

    __shared__ __align__(16) unsigned short Alds[2][BM * BK]; // 2 x 8 KB
    __shared__ __align__(16) unsigned short Blds[2][BN * BK]; // 2 x 8 KB
    __shared__ int   toks[BM];
    __shared__ float wgts[BM];

    int tid = threadIdx.x;
    if (tid < BM) {
        int g = row0 + tid;
        bool ok = g < cnt;
        toks[tid] = ok ? tokl[e * TT + g] : 0;
        wgts[tid] = ok ? wl[e * TT + g] : 0.0f;
    }
    __syncthreads();

    const int lane = tid & 63;
    const int wv   = tid >> 6;
    const int wr   = wv >> 1, wc = wv & 1;
    const int mrow = wr * 64, ncol = wc * 64;

    f32x4 acc[4][4];
    #pragma unroll
    for (int m = 0; m < 4; ++m)
        #pragma unroll
        for (int n = 0; n < 4; ++n) acc[m][n] = (f32x4)0.0f;

    const unsigned short* wte = wt + (size_t)e * HH * HH + (size_t)(nb * BN) * HH;

    // Staging: dest byte = tid*16 (+4096 for second row-half); dest row =
    // tid>>2, dest chunk = tid&3. Inverse-swizzled SOURCE chunk:
    const int srow  = tid >> 2;
    const int schk  = (tid & 3) ^ (srow & 3);
    const int scol  = schk * 8;            // element offset within row
    const unsigned short* abase0 = xb + (size_t)toks[srow] * HH + scol;
    const unsigned short* abase1 = xb + (size_t)toks[srow + 64] * HH + scol;
    const unsigned short* bbase0 = wte + (size_t)srow * HH + scol;
    const unsigned short* bbase1 = wte + (size_t)(srow + 64) * HH + scol;
    const int ldst = tid * 16;             // linear LDS byte offset

#define STAGE(buf, k0)                                                         \
    {                                                                          \
        __builtin_amdgcn_global_load_lds(                                      \
            (const __attribute__((address_space(1))) void*)(abase0 + (k0)),    \
            (__attribute__((address_space(3))) void*)((char*)&Alds[buf][0] + ldst), \
            16, 0, 0);                                                         \
        __builtin_amdgcn_global_load_lds(                                      \
            (const __attribute__((address_space(1))) void*)(abase1 + (k0)),    \
            (__attribute__((address_space(3))) void*)((char*)&Alds[buf][0] + ldst + 4096), \
            16, 0, 0);                                                         \
        __builtin_amdgcn_global_load_lds(                                      \
            (const __attribute__((address_space(1))) void*)(bbase0 + (k0)),    \
            (__attribute__((address_space(3))) void*)((char*)&Blds[buf][0] + ldst), \
            16, 0, 0);                                                         \
        __builtin_amdgcn_global_load_lds(                                      \
            (const __attribute__((address_space(1))) void*)(bbase1 + (k0)),    \
            (__attribute__((address_space(3))) void*)((char*)&Blds[buf][0] + ldst + 4096), \
            16, 0, 0);                                                         \
    }

    // Swizzled read chunk: source chunk q=(lane>>4) lives at LDS chunk
    // q ^ (row&3), and row&3 == lane&3 for every fragment row.
    const int rchk = ((lane >> 4) ^ (lane & 3)) * 16;   // byte offset in row

#define COMPUTE(buf)                                                           \
    {                                                                          \
        short8 av[4], bv[4];                                                   \
        _Pragma("unroll")                                                      \
        for (int m = 0; m < 4; ++m)                                            \
            av[m] = *(const short8*)((const char*)&Alds[buf][0] + (mrow + m * 16 + (lane & 15)) * 64 + rchk); \
        _Pragma("unroll")                                                      \
        for (int n = 0; n < 4; ++n)                                            \
            bv[n] = *(const short8*)((const char*)&Blds[buf][0] + (ncol + n * 16 + (lane & 15)) * 64 + rchk); \
        _Pragma("unroll")                                                      \
        for (int m = 0; m < 4; ++m)                                            \
            _Pragma("unroll")                                                  \
            for (int n = 0; n < 4; ++n)                                        \
                acc[m][n] = __builtin_amdgcn_mfma_f32_16x16x32_bf16(av[m], bv[n], acc[m][n], 0, 0, 0); \
    }

    STAGE(0, 0);

    for (int kt = 0; kt < NT - 1; kt += 2) {
        STAGE(1, (kt + 1) * BK);
        asm volatile("s_waitcnt vmcnt(4)" ::: "memory");
        __builtin_amdgcn_sched_barrier(0);
        __builtin_amdgcn_s_barrier();
        __builtin_amdgcn_sched_barrier(0);
        COMPUTE(0);
        __builtin_amdgcn_sched_barrier(0);
        __builtin_amdgcn_s_barrier();
        __builtin_amdgcn_sched_barrier(0);
        if (kt + 2 < NT) {
            STAGE(0, (kt + 2) * BK);
            asm volatile("s_waitcnt vmcnt(4)" ::: "memory");
        } else {
            asm volatile("s_waitcnt vmcnt(0)" ::: "memory");
        }
        __builtin_amdgcn_sched_barrier(0);
        __builtin_amdgcn_s_barrier();
        __builtin_amdgcn_sched_barrier(0);
        COMPUTE(1);
        __builtin_amdgcn_sched_barrier(0);
        __builtin_amdgcn_s_barrier();
        __builtin_amdgcn_sched_barrier(0);
    }
    asm volatile("s_waitcnt vmcnt(0)" ::: "memory");
    __builtin_amdgcn_sched_barrier(0);

#undef STAGE
#undef COMPUTE

    // epilogue: C/D mapping col=lane&15, row=(lane>>4)*4+reg
    #pragma unroll
    for (int m = 0; m < 4; ++m) {
        int lr0 = mrow + m * 16 + ((lane >> 4) << 2);
        #pragma unroll
        for (int rg = 0; rg < 4; ++rg) {
            int lr = lr0 + rg;
            int tkn = toks[lr];
            float wg = wgts[lr];
            if (wg != 0.0f) {
                float* orow = out + (size_t)tkn * HH + nb * BN + ncol + (lane & 15);
                #pragma unroll
                for (int n = 0; n < 4; ++n)
                    atomicAdd(orow + n * 16, wg * acc[m][n][rg]);
            }
        }
    }
}

// ---------------------------------------------------------------------------
extern "C" void kernel_launch(void* const* d_in, const int* in_sizes, int n_in,
                              void* d_out, int out_size, void* d_ws, size_t ws_size,
                              hipStream_t stream) {
    const float* x  = (const float*)d_in[0];
    const float* gw = (const float*)d_in[1];
    const float* gb = (const float*)d_in[2];
    const float* ew = (const float*)d_in[3];
    const float* eb = (const float*)d_in[4];
    float* out    = (float*)d_out;
    float* logits = out + (size_t)TT * HH;

    char* w = (char*)d_ws;
    unsigned short* xb = (unsigned short*)w;                                   // 32 MB
    unsigned short* wt = (unsigned short*)(w + (size_t)TT * HH * 2);           // 16 MB
    char* p  = w + (size_t)TT * HH * 2 + (size_t)EE * HH * HH * 2;
    int*   counts = (int*)p;                                                   // 32 B (+pad)
    int*   tokl   = (int*)(p + 256);                                           // 512 KB
    float* wl     = (float*)(p + 256 + (size_t)EE * TT * 4);                   // 512 KB
    int*   tops_i = (int*)(p + 256 + 2 * (size_t)EE * TT * 4);                 // 64 KB
    float* tops_w = (float*)(p + 256 + 2 * (size_t)EE * TT * 4 + TT * 4);      // 64 KB

    hipMemsetAsync(counts, 0, 256, stream);
    hipLaunchKernelGGL(prep_kernel, dim3(2048 + TT / 4), dim3(256), 0, stream,
                       ew, wt, x, gw, gb, logits, tops_i, tops_w);
    hipLaunchKernelGGL(stream_lists_kernel, dim3(2048), dim3(256), 0, stream,
                       x, eb, tops_i, tops_w, counts, tokl, wl, xb, out);
    hipLaunchKernelGGL(moe_gemm_kernel, dim3(EE * (TT / BM) * (HH / BN)), dim3(256), 0, stream,
                       xb, wt, counts, tokl, wl, out);
}